// Round 1
// baseline (175.924 us; speedup 1.0000x reference)
//
#include <hip/hip_runtime.h>
#include <hip/hip_bf16.h>
#include <math.h>

// K[c,h,l] = sum_n W[c,h,n] * cos(Lambda[n]*l)
// GEMM: (512 x 4096) * (4096 x 8192), S generated on the fly.

typedef __bf16 bf16_t;
typedef bf16_t bf16x8 __attribute__((ext_vector_type(8)));
typedef float f32x4 __attribute__((ext_vector_type(4)));

#define NK 4096   // inner (n)
#define MH 512    // rows (c*h)
#define LO 8192   // output length (l)
#define BM 128
#define BN 128
#define BK 32
#define LDK 40    // padded LDS row (bf16 elems): 80B, 16B-aligned, 2-way banks

__global__ __launch_bounds__(256) void dlr_cosgemm(
    const float* __restrict__ W,
    const float* __restrict__ Lam,
    float* __restrict__ out)
{
    __shared__ uint32_t tbl[NK];            // packed (a<<16)|(e&0xffff): mu = a/2^13 + e*2^-29
    __shared__ bf16_t Al[2][BM][LDK];
    __shared__ bf16_t Sl[2][BN][LDK];

    const int tid = threadIdx.x;
    const int bid = blockIdx.x;
    // bijective swizzle: XCD (= bid%8 round-robin) keeps a single m-tile -> W slice L2-resident
    const int mt = (bid >> 1) & 3;
    const int nt = ((bid >> 3) << 1) | (bid & 1);
    const int m0 = mt * BM;
    const int n0 = nt * BN;

    // ---- fixed-point phase table: mu = Lam/2pi = a/8192 + eps, eps quantized to 2^-29 ----
    for (int i = tid; i < NK; i += 256) {
        double mu = (double)Lam[i] * 0.15915494309189535;
        int a = (int)rint(mu * 8192.0);
        int e = (int)rint((mu - (double)a * (1.0 / 8192.0)) * 536870912.0);
        e = e > 32767 ? 32767 : (e < -32768 ? -32768 : e);
        tbl[i] = ((uint32_t)a << 16) | ((uint32_t)e & 0xffffu);
    }

    // ---- per-thread constants ----
    // S staging: one k-lane per thread, 16 consecutive l (phase recurrence along l)
    const int skl = tid & 31;            // k within k-tile
    const int scg = tid >> 5;            // column group 0..7
    const int lbase = n0 + scg * 16;     // first l of this thread (fixed all kernel)
    const float l29 = (float)lbase * 0x1p-29f;
    // A staging: 2 threads per row, 16 f32 each
    const int arow = tid >> 1;
    const int akh = (tid & 1) * 16;
    const float* aptr = W + (size_t)(m0 + arow) * NK + akh;
    // wave decomposition: 4 waves in 2x2, each owns 64x64 (4x4 frags of 16x16)
    const int wid = tid >> 6;
    const int lane = tid & 63;
    const int wm = (wid >> 1) * 64;
    const int wn = (wid & 1) * 64;
    const int fr = lane & 15;
    const int fq = lane >> 4;

    f32x4 acc[4][4];
    #pragma unroll
    for (int i = 0; i < 4; ++i)
        #pragma unroll
        for (int j = 0; j < 4; ++j)
            acc[i][j] = f32x4{0.f, 0.f, 0.f, 0.f};

    __syncthreads();   // table ready

    auto stageS = [&](int buf, int k0) {
        uint32_t pk = tbl[k0 + skl];
        uint32_t a = pk >> 16;
        int e = (int)(short)(pk & 0xffffu);
        uint32_t prod = a * (uint32_t)lbase;              // exact: frac via integer mod 2^13
        float f = fmaf((float)(prod & 8191u), 0x1p-13f, (float)e * l29);
        f -= rintf(f);                                    // f = frac(mu*lbase) in [-0.5,0.5]
        float mu = fmaf((float)a, 0x1p-13f, (float)e * 0x1p-29f);
        #pragma unroll
        for (int j = 0; j < 16; ++j) {
            // v_cos_f32 input is in REVOLUTIONS: cos(2*pi*f) = cos(Lam_k * l)
            Sl[buf][scg * 16 + j][skl] = (bf16_t)__builtin_amdgcn_cosf(f);
            f += mu;
            f -= rintf(f);
        }
    };

    auto stageA = [&](int buf, int k0) {
        const float4* g = (const float4*)(aptr + k0);
        float4 v0 = g[0], v1 = g[1], v2 = g[2], v3 = g[3];
        bf16x8 p0, p1;
        p0[0] = (bf16_t)v0.x; p0[1] = (bf16_t)v0.y; p0[2] = (bf16_t)v0.z; p0[3] = (bf16_t)v0.w;
        p0[4] = (bf16_t)v1.x; p0[5] = (bf16_t)v1.y; p0[6] = (bf16_t)v1.z; p0[7] = (bf16_t)v1.w;
        p1[0] = (bf16_t)v2.x; p1[1] = (bf16_t)v2.y; p1[2] = (bf16_t)v2.z; p1[3] = (bf16_t)v2.w;
        p1[4] = (bf16_t)v3.x; p1[5] = (bf16_t)v3.y; p1[6] = (bf16_t)v3.z; p1[7] = (bf16_t)v3.w;
        *(bf16x8*)&Al[buf][arow][akh] = p0;
        *(bf16x8*)&Al[buf][arow][akh + 8] = p1;
    };

    auto compute = [&](int buf) {
        bf16x8 af[4], bfv[4];
        #pragma unroll
        for (int mi = 0; mi < 4; ++mi)
            af[mi] = *(const bf16x8*)&Al[buf][wm + mi * 16 + fr][fq * 8];
        #pragma unroll
        for (int ni = 0; ni < 4; ++ni)
            bfv[ni] = *(const bf16x8*)&Sl[buf][wn + ni * 16 + fr][fq * 8];
        #pragma unroll
        for (int mi = 0; mi < 4; ++mi)
            #pragma unroll
            for (int ni = 0; ni < 4; ++ni)
                acc[mi][ni] = __builtin_amdgcn_mfma_f32_16x16x32_bf16(
                    af[mi], bfv[ni], acc[mi][ni], 0, 0, 0);
    };

    // ---- main loop: double-buffered, one barrier per K-step ----
    stageA(0, 0);
    stageS(0, 0);
    __syncthreads();

    #pragma unroll 2
    for (int it = 0; it < 127; ++it) {
        const int cur = it & 1;
        stageA(cur ^ 1, (it + 1) * BK);
        stageS(cur ^ 1, (it + 1) * BK);
        compute(cur);
        __syncthreads();
    }
    compute(1);

    // ---- epilogue: C/D layout col=lane&15, row=(lane>>4)*4+reg ----
    #pragma unroll
    for (int mi = 0; mi < 4; ++mi) {
        #pragma unroll
        for (int ni = 0; ni < 4; ++ni) {
            const int row = m0 + wm + mi * 16 + fq * 4;
            const int col = n0 + wn + ni * 16 + fr;
            #pragma unroll
            for (int rr = 0; rr < 4; ++rr)
                out[(size_t)(row + rr) * LO + col] = acc[mi][ni][rr];
        }
    }
}

extern "C" void kernel_launch(void* const* d_in, const int* in_sizes, int n_in,
                              void* d_out, int out_size, void* d_ws, size_t ws_size,
                              hipStream_t stream) {
    const float* W = (const float*)d_in[0];
    const float* Lam = (const float*)d_in[1];
    float* out = (float*)d_out;
    // L is fixed at 8192 by the problem setup (d_in[2] unused).
    dlr_cosgemm<<<dim3(256), dim3(256), 0, stream>>>(W, Lam, out);
}

// Round 2
// 157.010 us; speedup vs baseline: 1.1205x; 1.1205x over previous
//
#include <hip/hip_runtime.h>
#include <hip/hip_bf16.h>
#include <math.h>

// K[c,h,l] = sum_n W[c,h,n] * cos(Lambda[n]*l)
// GEMM (512 x 4096) x (4096 x 8192); S generated in-LDS via Chebyshev recurrence.

typedef __bf16 bf16_t;
typedef bf16_t bf16x8 __attribute__((ext_vector_type(8)));
typedef float f32x16 __attribute__((ext_vector_type(16)));

#define NK 4096
#define LO 8192
#define BM 128
#define BN 128
#define BK 32
#define LDK 40   // bf16 elems/row: 80B stride, 16B-aligned, b128 reads at conflict floor

__device__ __forceinline__ uint32_t cvt_pk(float lo, float hi) {
    uint32_t r;
    asm("v_cvt_pk_bf16_f32 %0, %1, %2" : "=v"(r) : "v"(lo), "v"(hi));
    return r;
}

__global__ __launch_bounds__(256) void dlr_cosgemm(
    const float* __restrict__ W,
    const float* __restrict__ Lam,
    float* __restrict__ out)
{
    __shared__ uint32_t tbl[NK];   // (a<<16)|(e&0xffff): mu = a/2^13 + e*2^-29
    __shared__ float    cheb[NK];  // 2*cos(2*pi*mu_k)  (Chebyshev coefficient)
    __shared__ bf16_t   Al[2][BM][LDK];
    __shared__ bf16_t   Sl[2][BN][LDK];

    const int tid = threadIdx.x;
    const int bid = blockIdx.x;
    // XCD swizzle: each XCD handles one m-tile (2MB W slice stays L2-resident)
    const int mt = (bid >> 1) & 3;
    const int nt = ((bid >> 3) << 1) | (bid & 1);
    const int m0 = mt * BM;
    const int n0 = nt * BN;

    // ---- per-block tables (once) ----
    for (int i = tid; i < NK; i += 256) {
        double mu = (double)Lam[i] * 0.15915494309189535;
        int a = (int)rint(mu * 8192.0);
        double eps = mu - (double)a * (1.0 / 8192.0);
        int e = (int)rint(eps * 536870912.0);
        e = e > 32767 ? 32767 : (e < -32768 ? -32768 : e);
        tbl[i] = ((uint32_t)a << 16) | ((uint32_t)e & 0xffffu);
        double fr = mu - rint(mu);
        cheb[i] = 2.0f * __builtin_amdgcn_cosf((float)fr);
    }

    // ---- S staging: each thread owns 2 adjacent k, 8 adjacent l ----
    const int skk  = (tid & 15) * 2;
    const int srow = (tid >> 4) * 8;
    const int sl0  = n0 + srow;
    const float l29 = (float)sl0 * 0x1p-29f;

    // ---- A staging: 2 threads/row, 16 f32 each ----
    const int arow = tid >> 1;
    const int akh  = (tid & 1) * 16;
    const float* aptr = W + (size_t)(m0 + arow) * NK + akh;

    // ---- wave decomposition: 2x2 waves of 64x64, 2x2 frags of 32x32 ----
    const int wid = tid >> 6;
    const int lane = tid & 63;
    const int wm = (wid >> 1) * 64;
    const int wn = (wid & 1) * 64;
    const int r31 = lane & 31;
    const int hi8 = (lane >> 5) * 8;

    f32x16 acc[2][2];
    #pragma unroll
    for (int i = 0; i < 2; ++i)
        #pragma unroll
        for (int j = 0; j < 2; ++j)
            #pragma unroll
            for (int r = 0; r < 16; ++r)
                acc[i][j][r] = 0.f;

    __syncthreads();   // tables ready

    auto chain8 = [&](int k, float* c) {
        uint32_t pk = tbl[k];
        float c2 = cheb[k];
        float ef = (float)(int)(short)(pk & 0xffffu);
        uint32_t a = pk >> 16;
        uint32_t prod = a * (uint32_t)sl0;                       // exact phase mod 2^13
        float f0 = fmaf((float)(prod & 8191u), 0x1p-13f, ef * l29);
        f0 -= rintf(f0);
        float mu = fmaf((float)a, 0x1p-13f, ef * 0x1p-29f);
        float f1 = f0 + mu; f1 -= rintf(f1);
        c[0] = __builtin_amdgcn_cosf(f0);                        // revolutions
        c[1] = __builtin_amdgcn_cosf(f1);
        #pragma unroll
        for (int j = 2; j < 8; ++j) c[j] = fmaf(c2, c[j - 1], -c[j - 2]);
    };

    auto stageS = [&](int buf, int k0) {
        float ca[8], cb[8];
        chain8(k0 + skk, ca);
        chain8(k0 + skk + 1, cb);
        #pragma unroll
        for (int j = 0; j < 8; ++j)
            *(uint32_t*)&Sl[buf][srow + j][skk] = cvt_pk(ca[j], cb[j]);
    };

    auto stageA = [&](int buf, int k0) {
        const float4* g = (const float4*)(aptr + k0);
        float4 v0 = g[0], v1 = g[1], v2 = g[2], v3 = g[3];
        uint4 q0, q1;
        q0.x = cvt_pk(v0.x, v0.y); q0.y = cvt_pk(v0.z, v0.w);
        q0.z = cvt_pk(v1.x, v1.y); q0.w = cvt_pk(v1.z, v1.w);
        q1.x = cvt_pk(v2.x, v2.y); q1.y = cvt_pk(v2.z, v2.w);
        q1.z = cvt_pk(v3.x, v3.y); q1.w = cvt_pk(v3.z, v3.w);
        *(uint4*)&Al[buf][arow][akh]     = q0;
        *(uint4*)&Al[buf][arow][akh + 8] = q1;
    };

    auto compute = [&](int buf) {
        #pragma unroll
        for (int ks = 0; ks < 2; ++ks) {
            const int ko = ks * 16 + hi8;
            bf16x8 a0 = *(const bf16x8*)&Al[buf][wm + r31][ko];
            bf16x8 a1 = *(const bf16x8*)&Al[buf][wm + 32 + r31][ko];
            bf16x8 b0 = *(const bf16x8*)&Sl[buf][wn + r31][ko];
            bf16x8 b1 = *(const bf16x8*)&Sl[buf][wn + 32 + r31][ko];
            acc[0][0] = __builtin_amdgcn_mfma_f32_32x32x16_bf16(a0, b0, acc[0][0], 0, 0, 0);
            acc[0][1] = __builtin_amdgcn_mfma_f32_32x32x16_bf16(a0, b1, acc[0][1], 0, 0, 0);
            acc[1][0] = __builtin_amdgcn_mfma_f32_32x32x16_bf16(a1, b0, acc[1][0], 0, 0, 0);
            acc[1][1] = __builtin_amdgcn_mfma_f32_32x32x16_bf16(a1, b1, acc[1][1], 0, 0, 0);
        }
    };

    // ---- main loop: double-buffered, one barrier per K-step ----
    stageA(0, 0);
    stageS(0, 0);
    __syncthreads();

    #pragma unroll 2
    for (int it = 0; it < 127; ++it) {
        const int cur = it & 1;
        stageA(cur ^ 1, (it + 1) * BK);
        stageS(cur ^ 1, (it + 1) * BK);
        compute(cur);
        __syncthreads();
    }
    compute(1);

    // ---- epilogue: 32x32 C/D layout col=lane&31, row=(reg&3)+8*(reg>>2)+4*(lane>>5) ----
    #pragma unroll
    for (int mi = 0; mi < 2; ++mi) {
        #pragma unroll
        for (int ni = 0; ni < 2; ++ni) {
            const int col = n0 + wn + ni * 32 + r31;
            const int rbase = m0 + wm + mi * 32 + 4 * (lane >> 5);
            #pragma unroll
            for (int reg = 0; reg < 16; ++reg) {
                const int row = rbase + (reg & 3) + 8 * (reg >> 2);
                out[(size_t)row * LO + col] = acc[mi][ni][reg];
            }
        }
    }
}

extern "C" void kernel_launch(void* const* d_in, const int* in_sizes, int n_in,
                              void* d_out, int out_size, void* d_ws, size_t ws_size,
                              hipStream_t stream) {
    const float* W = (const float*)d_in[0];
    const float* Lam = (const float*)d_in[1];
    float* out = (float*)d_out;
    dlr_cosgemm<<<dim3(256), dim3(256), 0, stream>>>(W, Lam, out);
}

// Round 3
// 132.836 us; speedup vs baseline: 1.3244x; 1.1820x over previous
//
#include <hip/hip_runtime.h>
#include <hip/hip_bf16.h>
#include <math.h>

// K[c,h,l] = sum_n W[c,h,n] * cos(Lambda[n]*l)
// GEMM (512 x 4096) x (4096 x 8192); S generated in-LDS (Chebyshev chains),
// A (W as bf16) read directly global->regs from a precomputed ws copy.

typedef __bf16 bf16_t;
typedef bf16_t bf16x8 __attribute__((ext_vector_type(8)));
typedef float f32x16 __attribute__((ext_vector_type(16)));

#define NK 4096
#define MH 512
#define LO 8192
#define BM 128
#define BN 128
#define BK 64
#define LDK 72   // Sl row: 144B = 9*16B (odd 16B multiple -> conflict-free b128)

__device__ __forceinline__ uint32_t cvt_pk(float lo, float hi) {
    uint32_t r;
    asm("v_cvt_pk_bf16_f32 %0, %1, %2" : "=v"(r) : "v"(lo), "v"(hi));
    return r;
}

// ---------------- precompute: phase tables + W -> bf16 ----------------
__global__ __launch_bounds__(256) void dlr_prep(
    const float* __restrict__ W, const float* __restrict__ Lam, void* __restrict__ ws)
{
    uint32_t* tbl  = (uint32_t*)ws;
    float*    cheb = (float*)((char*)ws + NK * 4);
    bf16_t*   Wb   = (bf16_t*)((char*)ws + NK * 8);
    const int gid = blockIdx.x * 256 + threadIdx.x;
    if (gid < NK) {
        double mu = (double)Lam[gid] * 0.15915494309189535;
        int a = (int)rint(mu * 8192.0);
        double eps = mu - (double)a * (1.0 / 8192.0);
        int e = (int)rint(eps * 536870912.0);
        e = e > 32767 ? 32767 : (e < -32768 ? -32768 : e);
        tbl[gid] = ((uint32_t)a << 16) | ((uint32_t)e & 0xffffu);
        double fr = mu - rint(mu);
        cheb[gid] = 2.0f * __builtin_amdgcn_cosf((float)fr);
    }
    size_t base = (size_t)gid * 8;
    if (base < (size_t)MH * NK) {
        const float4* s = (const float4*)(W + base);
        float4 v0 = s[0], v1 = s[1];
        uint4 q;
        q.x = cvt_pk(v0.x, v0.y); q.y = cvt_pk(v0.z, v0.w);
        q.z = cvt_pk(v1.x, v1.y); q.w = cvt_pk(v1.z, v1.w);
        *(uint4*)(Wb + base) = q;
    }
}

// ---------------- main GEMM ----------------
__global__ __launch_bounds__(512, 2) void dlr_main(
    const void* __restrict__ ws, float* __restrict__ out)
{
    const uint32_t* tbl  = (const uint32_t*)ws;
    const float*    cheb = (const float*)((const char*)ws + NK * 4);
    const bf16_t*   Wb   = (const bf16_t*)((const char*)ws + NK * 8);

    __shared__ bf16_t Sl[2][BN][LDK];
    __shared__ float  red[BM][BN + 2];

    const int tid = threadIdx.x;
    const int bid = blockIdx.x;
    // XCD swizzle: 2 XCDs per m-tile -> 1MB bf16 W slice L2-resident
    const int mt = (bid >> 1) & 3;
    const int nt = ((bid >> 3) << 1) | (bid & 1);
    const int m0 = mt * BM;
    const int n0 = nt * BN;

    // ---- S staging: thread owns k-pair skk, 8 adjacent l ----
    const int skk  = (tid & 31) * 2;
    const int srow = (tid >> 5) * 8;
    const int sl0  = n0 + srow;
    const float l29 = (float)sl0 * 0x1p-29f;

    // ---- waves: 2x2 output tiles of 64x64, x2 K-groups ----
    const int wid  = tid >> 6;
    const int lane = tid & 63;
    const int kg   = wid & 1;
    const int wn   = ((wid >> 1) & 1) * 64;
    const int wm   = ((wid >> 2) & 1) * 64;
    const int r31  = lane & 31;
    const int hi8  = (lane >> 5) * 8;

    // A-frag base pointers (fixed per thread; advance 64 elems/iter)
    const bf16_t* abase[2][2];
    #pragma unroll
    for (int mi = 0; mi < 2; ++mi)
        #pragma unroll
        for (int ks = 0; ks < 2; ++ks)
            abase[mi][ks] = Wb + (size_t)(m0 + wm + mi * 32 + r31) * NK
                               + kg * 32 + ks * 16 + hi8;

    f32x16 acc[2][2];
    #pragma unroll
    for (int i = 0; i < 2; ++i)
        #pragma unroll
        for (int j = 0; j < 2; ++j)
            #pragma unroll
            for (int r = 0; r < 16; ++r)
                acc[i][j][r] = 0.f;

    uint32_t tA, tB; float cA, cB;       // table regs for the tile being staged
    auto loadTbl = [&](int t) {
        int k = t * BK + skk;
        tA = tbl[k]; tB = tbl[k + 1];
        cA = cheb[k]; cB = cheb[k + 1];
    };

    auto chain8 = [&](uint32_t pk, float c2, float* c) {
        float ef = (float)(int)(short)(pk & 0xffffu);
        uint32_t a = pk >> 16;
        uint32_t prod = a * (uint32_t)sl0;                       // exact mod 2^13
        float f0 = fmaf((float)(prod & 8191u), 0x1p-13f, ef * l29);
        f0 -= rintf(f0);
        float mu = fmaf((float)a, 0x1p-13f, ef * 0x1p-29f);
        float f1 = f0 + mu; f1 -= rintf(f1);
        c[0] = __builtin_amdgcn_cosf(f0);                        // revolutions
        c[1] = __builtin_amdgcn_cosf(f1);
        #pragma unroll
        for (int j = 2; j < 8; ++j) c[j] = fmaf(c2, c[j - 1], -c[j - 2]);
    };

    auto stageS = [&](int buf) {
        float ca[8], cb[8];
        chain8(tA, cA, ca);
        chain8(tB, cB, cb);
        #pragma unroll
        for (int j = 0; j < 8; ++j)
            *(uint32_t*)&Sl[buf][srow + j][skk] = cvt_pk(ca[j], cb[j]);
    };

    bf16x8 aCur[2][2], aNxt[2][2];
    auto loadA = [&](bf16x8 a[2][2], int it) {
        #pragma unroll
        for (int mi = 0; mi < 2; ++mi)
            #pragma unroll
            for (int ks = 0; ks < 2; ++ks)
                a[mi][ks] = *(const bf16x8*)(abase[mi][ks] + (size_t)it * BK);
    };

    auto compute = [&](int buf, bf16x8 a[2][2]) {
        bf16x8 bfr[2][2];
        #pragma unroll
        for (int ks = 0; ks < 2; ++ks)
            #pragma unroll
            for (int ni = 0; ni < 2; ++ni)
                bfr[ni][ks] = *(const bf16x8*)&Sl[buf][wn + ni * 32 + r31]
                                                 [kg * 32 + ks * 16 + hi8];
        #pragma unroll
        for (int ks = 0; ks < 2; ++ks)
            #pragma unroll
            for (int mi = 0; mi < 2; ++mi)
                #pragma unroll
                for (int ni = 0; ni < 2; ++ni)
                    acc[mi][ni] = __builtin_amdgcn_mfma_f32_32x32x16_bf16(
                        a[mi][ks], bfr[ni][ks], acc[mi][ni], 0, 0, 0);
    };

    // ---- prologue ----
    loadTbl(0);
    loadA(aCur, 0);
    stageS(0);
    loadTbl(1);
    loadA(aNxt, 0);   // init only (silence uninit use at it=63)
    __syncthreads();

    // ---- main loop: 64 iters of BK=64, double-buffered S, prefetched A ----
    #pragma unroll 2
    for (int it = 0; it < 64; ++it) {
        const int cur = it & 1;
        if (it < 63) {
            loadA(aNxt, it + 1);
            stageS(cur ^ 1);
        }
        if (it < 62) loadTbl(it + 2);
        compute(cur, aCur);
        #pragma unroll
        for (int mi = 0; mi < 2; ++mi)
            #pragma unroll
            for (int ks = 0; ks < 2; ++ks)
                aCur[mi][ks] = aNxt[mi][ks];
        __syncthreads();
    }

    // ---- split-K reduce via LDS, then store ----
    if (kg == 1) {
        #pragma unroll
        for (int mi = 0; mi < 2; ++mi)
            #pragma unroll
            for (int ni = 0; ni < 2; ++ni)
                #pragma unroll
                for (int rr = 0; rr < 16; ++rr) {
                    const int row = wm + mi * 32 + (rr & 3) + 8 * (rr >> 2) + 4 * (lane >> 5);
                    red[row][wn + ni * 32 + r31] = acc[mi][ni][rr];
                }
    }
    __syncthreads();
    if (kg == 0) {
        #pragma unroll
        for (int mi = 0; mi < 2; ++mi)
            #pragma unroll
            for (int ni = 0; ni < 2; ++ni) {
                const int col = n0 + wn + ni * 32 + r31;
                #pragma unroll
                for (int rr = 0; rr < 16; ++rr) {
                    const int row = wm + mi * 32 + (rr & 3) + 8 * (rr >> 2) + 4 * (lane >> 5);
                    out[(size_t)(m0 + row) * LO + col] =
                        acc[mi][ni][rr] + red[row][wn + ni * 32 + r31];
                }
            }
    }
}

// ---------------- fallback (round-2 kernel) if ws too small ----------------
__global__ __launch_bounds__(256) void dlr_fb(
    const float* __restrict__ W, const float* __restrict__ Lam, float* __restrict__ out)
{
    __shared__ uint32_t tbl[NK];
    __shared__ float    cheb[NK];
    __shared__ bf16_t   Al[2][BM][40];
    __shared__ bf16_t   Slf[2][BN][40];

    const int tid = threadIdx.x;
    const int bid = blockIdx.x;
    const int mt = (bid >> 1) & 3;
    const int nt = ((bid >> 3) << 1) | (bid & 1);
    const int m0 = mt * BM;
    const int n0 = nt * BN;

    for (int i = tid; i < NK; i += 256) {
        double mu = (double)Lam[i] * 0.15915494309189535;
        int a = (int)rint(mu * 8192.0);
        double eps = mu - (double)a * (1.0 / 8192.0);
        int e = (int)rint(eps * 536870912.0);
        e = e > 32767 ? 32767 : (e < -32768 ? -32768 : e);
        tbl[i] = ((uint32_t)a << 16) | ((uint32_t)e & 0xffffu);
        double fr = mu - rint(mu);
        cheb[i] = 2.0f * __builtin_amdgcn_cosf((float)fr);
    }

    const int skk  = (tid & 15) * 2;
    const int srow = (tid >> 4) * 8;
    const int sl0  = n0 + srow;
    const float l29 = (float)sl0 * 0x1p-29f;
    const int arow = tid >> 1;
    const int akh  = (tid & 1) * 16;
    const float* aptr = W + (size_t)(m0 + arow) * NK + akh;
    const int wid = tid >> 6;
    const int lane = tid & 63;
    const int wm = (wid >> 1) * 64;
    const int wn = (wid & 1) * 64;
    const int r31 = lane & 31;
    const int hi8 = (lane >> 5) * 8;

    f32x16 acc[2][2];
    #pragma unroll
    for (int i = 0; i < 2; ++i)
        #pragma unroll
        for (int j = 0; j < 2; ++j)
            #pragma unroll
            for (int r = 0; r < 16; ++r) acc[i][j][r] = 0.f;
    __syncthreads();

    auto chain8 = [&](int k, float* c) {
        uint32_t pk = tbl[k];
        float c2 = cheb[k];
        float ef = (float)(int)(short)(pk & 0xffffu);
        uint32_t a = pk >> 16;
        uint32_t prod = a * (uint32_t)sl0;
        float f0 = fmaf((float)(prod & 8191u), 0x1p-13f, ef * l29);
        f0 -= rintf(f0);
        float mu = fmaf((float)a, 0x1p-13f, ef * 0x1p-29f);
        float f1 = f0 + mu; f1 -= rintf(f1);
        c[0] = __builtin_amdgcn_cosf(f0);
        c[1] = __builtin_amdgcn_cosf(f1);
        #pragma unroll
        for (int j = 2; j < 8; ++j) c[j] = fmaf(c2, c[j - 1], -c[j - 2]);
    };
    auto stageS = [&](int buf, int k0) {
        float ca[8], cb[8];
        chain8(k0 + skk, ca);
        chain8(k0 + skk + 1, cb);
        #pragma unroll
        for (int j = 0; j < 8; ++j)
            *(uint32_t*)&Slf[buf][srow + j][skk] = cvt_pk(ca[j], cb[j]);
    };
    auto stageA = [&](int buf, int k0) {
        const float4* g = (const float4*)(aptr + k0);
        float4 v0 = g[0], v1 = g[1], v2 = g[2], v3 = g[3];
        uint4 q0, q1;
        q0.x = cvt_pk(v0.x, v0.y); q0.y = cvt_pk(v0.z, v0.w);
        q0.z = cvt_pk(v1.x, v1.y); q0.w = cvt_pk(v1.z, v1.w);
        q1.x = cvt_pk(v2.x, v2.y); q1.y = cvt_pk(v2.z, v2.w);
        q1.z = cvt_pk(v3.x, v3.y); q1.w = cvt_pk(v3.z, v3.w);
        *(uint4*)&Al[buf][arow][akh]     = q0;
        *(uint4*)&Al[buf][arow][akh + 8] = q1;
    };
    auto compute = [&](int buf) {
        #pragma unroll
        for (int ks = 0; ks < 2; ++ks) {
            const int ko = ks * 16 + hi8;
            bf16x8 a0 = *(const bf16x8*)&Al[buf][wm + r31][ko];
            bf16x8 a1 = *(const bf16x8*)&Al[buf][wm + 32 + r31][ko];
            bf16x8 b0 = *(const bf16x8*)&Slf[buf][wn + r31][ko];
            bf16x8 b1 = *(const bf16x8*)&Slf[buf][wn + 32 + r31][ko];
            acc[0][0] = __builtin_amdgcn_mfma_f32_32x32x16_bf16(a0, b0, acc[0][0], 0, 0, 0);
            acc[0][1] = __builtin_amdgcn_mfma_f32_32x32x16_bf16(a0, b1, acc[0][1], 0, 0, 0);
            acc[1][0] = __builtin_amdgcn_mfma_f32_32x32x16_bf16(a1, b0, acc[1][0], 0, 0, 0);
            acc[1][1] = __builtin_amdgcn_mfma_f32_32x32x16_bf16(a1, b1, acc[1][1], 0, 0, 0);
        }
    };

    stageA(0, 0);
    stageS(0, 0);
    __syncthreads();
    #pragma unroll 2
    for (int it = 0; it < 127; ++it) {
        const int cur = it & 1;
        stageA(cur ^ 1, (it + 1) * 32);
        stageS(cur ^ 1, (it + 1) * 32);
        compute(cur);
        __syncthreads();
    }
    compute(1);

    #pragma unroll
    for (int mi = 0; mi < 2; ++mi)
        #pragma unroll
        for (int ni = 0; ni < 2; ++ni) {
            const int col = n0 + wn + ni * 32 + r31;
            const int rbase = m0 + wm + mi * 32 + 4 * (lane >> 5);
            #pragma unroll
            for (int reg = 0; reg < 16; ++reg) {
                const int row = rbase + (reg & 3) + 8 * (reg >> 2);
                out[(size_t)row * LO + col] = acc[mi][ni][reg];
            }
        }
}

extern "C" void kernel_launch(void* const* d_in, const int* in_sizes, int n_in,
                              void* d_out, int out_size, void* d_ws, size_t ws_size,
                              hipStream_t stream) {
    const float* W = (const float*)d_in[0];
    const float* Lam = (const float*)d_in[1];
    float* out = (float*)d_out;
    const size_t need = (size_t)NK * 8 + (size_t)MH * NK * 2;
    if (ws_size >= need) {
        dlr_prep<<<dim3(1024), dim3(256), 0, stream>>>(W, Lam, d_ws);
        dlr_main<<<dim3(256), dim3(512), 0, stream>>>(d_ws, out);
    } else {
        dlr_fb<<<dim3(256), dim3(256), 0, stream>>>(W, Lam, out);
    }
}